// Round 7
// baseline (425.701 us; speedup 1.0000x reference)
//
#include <hip/hip_runtime.h>

#define B_   32
#define L_   1024
#define CD_  256
#define ZD_  256
#define P_   12
#define NS_  9     // 1 positive + 8 negatives
#define TL_  64    // l-rows per block

typedef __attribute__((ext_vector_type(8))) short bf16x8;
typedef __attribute__((ext_vector_type(4))) float f32x4;

__device__ __forceinline__ unsigned short f2b(float f) {
    unsigned u = __float_as_uint(f);
    u += 0x7FFFu + ((u >> 16) & 1u);          // round-nearest-even
    return (unsigned short)(u >> 16);
}

// ws layout: ws[0]=loss acc, ws[1]=msum; WT bf16 @ byte 256; zbf bf16 @ byte 1573120
// Fused prep: blocks [0,384): W->WT transpose; [384,4480): z->bf16; block 4480: init
__global__ __launch_bounds__(256) void cnce_prep(
        const float* __restrict__ W, unsigned short* __restrict__ WT,
        const float* __restrict__ z, unsigned short* __restrict__ zbf,
        const int* __restrict__ length, float* __restrict__ ws) {
    const int blk = blockIdx.x;
    const int tid = threadIdx.x;
    if (blk < 384) {
        const int g = blk & 31;              // cc-group: cc0 = 8g
        const int p = blk >> 5;
        const int cc0 = g * 8;
        const float* src = W + (size_t)p * CD_ * ZD_ + (size_t)cc0 * ZD_ + tid;
        unsigned short h[8];
        #pragma unroll
        for (int i = 0; i < 8; ++i) h[i] = f2b(src[(size_t)i * ZD_]);
        unsigned short* dst = WT + ((size_t)(p * ZD_ + tid)) * CD_ + cc0;
        *(int4*)dst = *(const int4*)h;
    } else if (blk < 4480) {
        if (zbf) {
            size_t i = ((size_t)(blk - 384) * 256 + tid) * 8;
            float4 a = *(const float4*)(z + i), b = *(const float4*)(z + i + 4);
            unsigned short h[8] = { f2b(a.x), f2b(a.y), f2b(a.z), f2b(a.w),
                                    f2b(b.x), f2b(b.y), f2b(b.z), f2b(b.w) };
            *(int4*)(zbf + i) = *(const int4*)h;
        }
    } else {
        if (tid < 64) {
            int v = (tid < B_) ? length[tid] : 0;
            #pragma unroll
            for (int m = 1; m < 64; m <<= 1) v += __shfl_xor(v, m);
            if (tid == 0) { ws[0] = 0.f; ws[1] = (float)v; }
        }
    }
}

__global__ __launch_bounds__(512, 4) void cnce_main(
        const float* __restrict__ c, const float* __restrict__ z,
        const unsigned short* __restrict__ WT,
        const unsigned short* __restrict__ zbf,   // may be null (ws too small)
        const int* __restrict__ neg_shift,
        const int* __restrict__ length, float* __restrict__ ws) {
    // XCD swizzle: hw-block h -> work; XCD k gets 4 consecutive b (zbf slice L2-fits)
    const int h = blockIdx.x;
    const int work = ((h & 7) << 6) | (h >> 3);
    const int b  = work >> 4;
    const int l0 = (work & 15) * TL_;
    const int tid  = threadIdx.x;
    const int w    = tid >> 6;        // 0..7
    const int lane = tid & 63;
    const int hi   = lane >> 4;
    const int m    = lane & 15;
    const int g    = w & 3;           // row-group (16 l's)
    const int half = w >> 2;          // j-subset: 0 -> {pos,n0,n1,n2}, 1 -> {n3..n7}

    // [0,32768): c-tile bf16 [64][256] swizzled
    // [32768,65536): Wc bf16 [64 l][256 d] swizzled
    __shared__ char smem[65536];
    __shared__ float bufm[TL_], bufs[TL_];   // half1 partial lse
    char* wcb = smem + 32768;

    // ---- stage c tile once ----
    {
        const float4* csrc = (const float4*)(c + (size_t)(b * L_ + l0) * CD_);
        #pragma unroll
        for (int it = 0; it < 8; ++it) {
            int fi = tid + it * 512;
            int l  = fi >> 6;
            int k4 = fi & 63;
            float4 v = csrc[fi];
            unsigned short hh[4] = { f2b(v.x), f2b(v.y), f2b(v.z), f2b(v.w) };
            int byte = (l * 512 + k4 * 8) ^ ((l & 15) << 4);
            *(uint2*)(smem + byte) = *(const uint2*)hh;
        }
    }
    __syncthreads();

    const int len_b = length[b];
    const bool owner = (hi == (m >> 2));      // diag owner: col m, row m -> hi=m>>2
    const int  rsel  = m & 3;
    const int  r     = g * 16 + m;            // row within tile
    const int  gl    = l0 + r;                // global l

    // per-half shift table (compile-time indexed)
    int sh_loc[5];
    #pragma unroll
    for (int j2 = 0; j2 < 5; ++j2) {
        int idx = half ? (3 + j2) : (j2 - 1);
        sh_loc[j2] = (idx >= 0) ? neg_shift[idx] : 0;
    }

    const unsigned short* zbb = zbf ? zbf + (size_t)b * L_ * ZD_ : nullptr;
    const float* zbF = z + (size_t)b * L_ * ZD_;

    float lsum = 0.f;

    for (int p = 0; p < P_; ++p) {
        // ---- GEMM (operand-swapped): C'[d][l]; wave w owns d-range [w*32, w*32+32) ----
        f32x4 acc[2][4];
        #pragma unroll
        for (int mi = 0; mi < 2; ++mi)
            #pragma unroll
            for (int ni = 0; ni < 4; ++ni) acc[mi][ni] = (f32x4){0.f, 0.f, 0.f, 0.f};
        const unsigned short* WTp = WT + (size_t)p * ZD_ * CD_;
        #pragma unroll
        for (int kk = 0; kk < 8; ++kk) {
            bf16x8 wf[2], cfk[4];
            const int k0 = kk * 32 + hi * 8;
            #pragma unroll
            for (int mi = 0; mi < 2; ++mi) {
                int d = w * 32 + mi * 16 + m;
                wf[mi] = *(const bf16x8*)(WTp + (size_t)d * CD_ + k0);
            }
            #pragma unroll
            for (int ni = 0; ni < 4; ++ni) {
                int l = ni * 16 + m;
                int byte = (l * 512 + k0 * 2) ^ ((l & 15) << 4);
                cfk[ni] = *(const bf16x8*)(smem + byte);
            }
            #pragma unroll
            for (int mi = 0; mi < 2; ++mi)
                #pragma unroll
                for (int ni = 0; ni < 4; ++ni)
                    acc[mi][ni] = __builtin_amdgcn_mfma_f32_16x16x32_bf16(
                        wf[mi], cfk[ni], acc[mi][ni], 0, 0, 0);
        }
        __syncthreads();   // prev p: pav reads + buf reads done
        // ---- spill Wc bf16: lane holds (l fixed, 4 consecutive d) -> packed b64 ----
        #pragma unroll
        for (int mi = 0; mi < 2; ++mi)
            #pragma unroll
            for (int ni = 0; ni < 4; ++ni) {
                int l  = ni * 16 + m;
                int d0 = w * 32 + mi * 16 + hi * 4;
                unsigned short hh[4] = { f2b(acc[mi][ni][0]), f2b(acc[mi][ni][1]),
                                         f2b(acc[mi][ni][2]), f2b(acc[mi][ni][3]) };
                int byte = (l * 512 + d0 * 2) ^ ((l & 15) << 4);
                *(uint2*)(wcb + byte) = *(const uint2*)hh;
            }
        __syncthreads();   // Wc ready
        // ---- phase B: diag-MFMA; wave-pair (g, half) covers rows g*16.., j-subset ----
        bf16x8 pav[8];
        #pragma unroll
        for (int kk = 0; kk < 8; ++kk) {
            int l  = g * 16 + m;
            int byte = (l * 512 + kk * 64 + hi * 16) ^ ((l & 15) << 4);
            pav[kk] = *(const bf16x8*)(wcb + byte);
        }
        float scores[5];
        #pragma unroll
        for (int j2 = 0; j2 < 5; ++j2) {
            if (j2 == 4 && half == 0) { scores[4] = -3e38f; continue; }
            const int s = (j2 == 0 && half == 0) ? (p + 1) : sh_loc[j2];
            const int rowz = (l0 + g * 16 + m + s) & (L_ - 1);
            f32x4 e = {0.f, 0.f, 0.f, 0.f}, o = {0.f, 0.f, 0.f, 0.f};
            if (zbb) {
                const unsigned short* zr = zbb + (size_t)rowz * ZD_ + hi * 8;
                #pragma unroll
                for (int kk = 0; kk < 8; kk += 2) {
                    bf16x8 b0 = *(const bf16x8*)(zr + kk * 32);
                    bf16x8 b1 = *(const bf16x8*)(zr + kk * 32 + 32);
                    e = __builtin_amdgcn_mfma_f32_16x16x32_bf16(pav[kk],     b0, e, 0, 0, 0);
                    o = __builtin_amdgcn_mfma_f32_16x16x32_bf16(pav[kk + 1], b1, o, 0, 0, 0);
                }
            } else {
                const float* zr = zbF + (size_t)rowz * ZD_ + hi * 8;
                #pragma unroll
                for (int kk = 0; kk < 8; ++kk) {
                    float4 z0 = *(const float4*)(zr + kk * 32);
                    float4 z1 = *(const float4*)(zr + kk * 32 + 4);
                    unsigned short hh[8] = { f2b(z0.x), f2b(z0.y), f2b(z0.z), f2b(z0.w),
                                             f2b(z1.x), f2b(z1.y), f2b(z1.z), f2b(z1.w) };
                    bf16x8 bz = *(const bf16x8*)hh;
                    if (kk & 1) o = __builtin_amdgcn_mfma_f32_16x16x32_bf16(pav[kk], bz, o, 0, 0, 0);
                    else        e = __builtin_amdgcn_mfma_f32_16x16x32_bf16(pav[kk], bz, e, 0, 0, 0);
                }
            }
            scores[j2] = (rsel == 0) ? e[0] + o[0] : (rsel == 1) ? e[1] + o[1]
                       : (rsel == 2) ? e[2] + o[2] : e[3] + o[3];
        }
        // partial logsumexp over this half's subset
        float mx = scores[0];
        #pragma unroll
        for (int j2 = 1; j2 < 5; ++j2) mx = fmaxf(mx, scores[j2]);
        float se = 0.f;
        #pragma unroll
        for (int j2 = 0; j2 < 5; ++j2) se += __expf(scores[j2] - mx);
        if (half == 1 && owner) { bufm[r] = mx; bufs[r] = se; }
        __syncthreads();   // buf ready
        if (half == 0 && owner) {
            float m1 = bufm[r], s1 = bufs[r];
            float mt  = fmaxf(mx, m1);
            float set = se * __expf(mx - mt) + s1 * __expf(m1 - mt);
            if (gl < len_b) lsum += __logf(set) + mt - scores[0];
        }
    }
    if (half == 0) {
        #pragma unroll
        for (int sh = 1; sh < 64; sh <<= 1) lsum += __shfl_xor(lsum, sh);
        if (lane == 0) atomicAdd(&ws[0], lsum);
    }
}

__global__ void cnce_fin(const float* __restrict__ ws, float* __restrict__ out) {
    out[0] = ws[0] / ws[1];
}

extern "C" void kernel_launch(void* const* d_in, const int* in_sizes, int n_in,
                              void* d_out, int out_size, void* d_ws, size_t ws_size,
                              hipStream_t stream) {
    const float* c  = (const float*)d_in[0];
    const float* z  = (const float*)d_in[1];
    const float* W  = (const float*)d_in[2];
    const int* neg_shift = (const int*)d_in[3];
    const int* length    = (const int*)d_in[4];
    float* out = (float*)d_out;
    float* ws  = (float*)d_ws;
    unsigned short* WT = (unsigned short*)((char*)d_ws + 256);

    const size_t ZBF_OFF = 256 + (size_t)P_ * CD_ * ZD_ * 2;          // 1,573,120
    const size_t NEED    = ZBF_OFF + (size_t)B_ * L_ * ZD_ * 2;       // ~18.35 MB
    unsigned short* zbf = (ws_size >= NEED)
                        ? (unsigned short*)((char*)d_ws + ZBF_OFF) : nullptr;

    cnce_prep<<<4481, 256, 0, stream>>>(W, WT, z, zbf, length, ws);
    cnce_main<<<512, 512, 0, stream>>>(c, z, WT, zbf, neg_shift, length, ws);
    cnce_fin<<<1, 1, 0, stream>>>(ws, out);
}

// Round 9
// 409.469 us; speedup vs baseline: 1.0396x; 1.0396x over previous
//
#include <hip/hip_runtime.h>

#define B_   32
#define L_   1024
#define CD_  256
#define ZD_  256
#define P_   12
#define NS_  9     // 1 positive + 8 negatives
#define TL_  64    // l-rows per block

typedef __attribute__((ext_vector_type(8))) short bf16x8;
typedef __attribute__((ext_vector_type(4))) float f32x4;

__device__ __forceinline__ unsigned short f2b(float f) {
    unsigned u = __float_as_uint(f);
    u += 0x7FFFu + ((u >> 16) & 1u);          // round-nearest-even
    return (unsigned short)(u >> 16);
}

// ws layout: ws[0]=loss acc, ws[1]=msum; WT bf16 @ byte 256; zbf bf16 @ byte 1573120
// Fused prep: blocks [0,384): W->WT transpose; [384,4480): z->bf16; block 4480: init
__global__ __launch_bounds__(256) void cnce_prep(
        const float* __restrict__ W, unsigned short* __restrict__ WT,
        const float* __restrict__ z, unsigned short* __restrict__ zbf,
        const int* __restrict__ length, float* __restrict__ ws) {
    const int blk = blockIdx.x;
    const int tid = threadIdx.x;
    if (blk < 384) {
        const int g = blk & 31;              // cc-group: cc0 = 8g
        const int p = blk >> 5;
        const int cc0 = g * 8;
        const float* src = W + (size_t)p * CD_ * ZD_ + (size_t)cc0 * ZD_ + tid;
        unsigned short h[8];
        #pragma unroll
        for (int i = 0; i < 8; ++i) h[i] = f2b(src[(size_t)i * ZD_]);
        unsigned short* dst = WT + ((size_t)(p * ZD_ + tid)) * CD_ + cc0;
        *(int4*)dst = *(const int4*)h;
    } else if (blk < 4480) {
        if (zbf) {
            size_t i = ((size_t)(blk - 384) * 256 + tid) * 8;
            float4 a = *(const float4*)(z + i), b = *(const float4*)(z + i + 4);
            unsigned short h[8] = { f2b(a.x), f2b(a.y), f2b(a.z), f2b(a.w),
                                    f2b(b.x), f2b(b.y), f2b(b.z), f2b(b.w) };
            *(int4*)(zbf + i) = *(const int4*)h;
        }
    } else {
        if (tid < 64) {
            int v = (tid < B_) ? length[tid] : 0;
            #pragma unroll
            for (int m = 1; m < 64; m <<= 1) v += __shfl_xor(v, m);
            if (tid == 0) { ws[0] = 0.f; ws[1] = (float)v; }
        }
    }
}

__global__ __launch_bounds__(512, 2) void cnce_main(
        const float* __restrict__ c, const float* __restrict__ z,
        const unsigned short* __restrict__ WT,
        const unsigned short* __restrict__ zbf,   // may be null (ws too small)
        const int* __restrict__ neg_shift,
        const int* __restrict__ length, float* __restrict__ ws) {
    // XCD swizzle: hw-block h -> work; XCD k gets 4 consecutive b (zbf slice L2-fits)
    const int h = blockIdx.x;
    const int work = ((h & 7) << 6) | (h >> 3);
    const int b  = work >> 4;
    const int l0 = (work & 15) * TL_;
    const int tid  = threadIdx.x;
    const int w    = tid >> 6;        // 0..7
    const int lane = tid & 63;
    const int hi   = lane >> 4;
    const int m    = lane & 15;
    const int g    = w & 3;           // row-group (16 l's)
    const int half = w >> 2;          // j-subset: 0 -> {pos,n0,n1,n2}, 1 -> {n3..n7}

    // [0,32768): c-tile bf16 [64][256] swizzled
    // [32768,65536): Wc bf16 [64 l][256 d] swizzled
    __shared__ char smem[65536];
    __shared__ float bufm[TL_], bufs[TL_];   // half1 partial lse
    char* wcb = smem + 32768;

    // ---- stage c tile once ----
    {
        const float4* csrc = (const float4*)(c + (size_t)(b * L_ + l0) * CD_);
        #pragma unroll
        for (int it = 0; it < 8; ++it) {
            int fi = tid + it * 512;
            int l  = fi >> 6;
            int k4 = fi & 63;
            float4 v = csrc[fi];
            unsigned short hh[4] = { f2b(v.x), f2b(v.y), f2b(v.z), f2b(v.w) };
            int byte = (l * 512 + k4 * 8) ^ ((l & 15) << 4);
            *(uint2*)(smem + byte) = *(const uint2*)hh;
        }
    }
    __syncthreads();

    const int len_b = length[b];
    const bool owner = (hi == (m >> 2));      // diag owner: col m, row m -> hi=m>>2
    const int  rsel  = m & 3;
    const int  r     = g * 16 + m;            // row within tile
    const int  gl    = l0 + r;                // global l

    // per-half shift table (compile-time indexed)
    int sh_loc[5];
    #pragma unroll
    for (int j2 = 0; j2 < 5; ++j2) {
        int idx = half ? (3 + j2) : (j2 - 1);
        sh_loc[j2] = (idx >= 0) ? neg_shift[idx] : 0;
    }

    const unsigned short* zbb = zbf ? zbf + (size_t)b * L_ * ZD_ : nullptr;
    const float* zbF = z + (size_t)b * L_ * ZD_;

    float lsum = 0.f;

    for (int p = 0; p < P_; ++p) {
        // ---- GEMM (operand-swapped): C'[d][l]; wave w owns d-range [w*32, w*32+32) ----
        f32x4 acc[2][4];
        #pragma unroll
        for (int mi = 0; mi < 2; ++mi)
            #pragma unroll
            for (int ni = 0; ni < 4; ++ni) acc[mi][ni] = (f32x4){0.f, 0.f, 0.f, 0.f};
        const unsigned short* WTp = WT + (size_t)p * ZD_ * CD_;
        #pragma unroll
        for (int kk = 0; kk < 8; ++kk) {
            bf16x8 wf[2], cfk[4];
            const int k0 = kk * 32 + hi * 8;
            #pragma unroll
            for (int mi = 0; mi < 2; ++mi) {
                int d = w * 32 + mi * 16 + m;
                wf[mi] = *(const bf16x8*)(WTp + (size_t)d * CD_ + k0);
            }
            #pragma unroll
            for (int ni = 0; ni < 4; ++ni) {
                int l = ni * 16 + m;
                int byte = (l * 512 + k0 * 2) ^ ((l & 15) << 4);
                cfk[ni] = *(const bf16x8*)(smem + byte);
            }
            #pragma unroll
            for (int mi = 0; mi < 2; ++mi)
                #pragma unroll
                for (int ni = 0; ni < 4; ++ni)
                    acc[mi][ni] = __builtin_amdgcn_mfma_f32_16x16x32_bf16(
                        wf[mi], cfk[ni], acc[mi][ni], 0, 0, 0);
        }
        __syncthreads();   // prev p: pav reads + buf reads done
        // ---- spill Wc bf16: lane holds (l fixed, 4 consecutive d) -> packed b64 ----
        #pragma unroll
        for (int mi = 0; mi < 2; ++mi)
            #pragma unroll
            for (int ni = 0; ni < 4; ++ni) {
                int l  = ni * 16 + m;
                int d0 = w * 32 + mi * 16 + hi * 4;
                unsigned short hh[4] = { f2b(acc[mi][ni][0]), f2b(acc[mi][ni][1]),
                                         f2b(acc[mi][ni][2]), f2b(acc[mi][ni][3]) };
                int byte = (l * 512 + d0 * 2) ^ ((l & 15) << 4);
                *(uint2*)(wcb + byte) = *(const uint2*)hh;
            }
        __syncthreads();   // Wc ready
        // ---- phase B: diag-MFMA; wave-pair (g, half) covers rows g*16.., j-subset ----
        bf16x8 pav[8];
        #pragma unroll
        for (int kk = 0; kk < 8; ++kk) {
            int l  = g * 16 + m;
            int byte = (l * 512 + kk * 64 + hi * 16) ^ ((l & 15) << 4);
            pav[kk] = *(const bf16x8*)(wcb + byte);
        }
        float scores[5];
        #pragma unroll
        for (int j2 = 0; j2 < 5; ++j2) {
            if (j2 == 4 && half == 0) { scores[4] = -3e38f; continue; }
            const int s = (j2 == 0 && half == 0) ? (p + 1) : sh_loc[j2];
            const int rowz = (l0 + g * 16 + m + s) & (L_ - 1);
            f32x4 e = {0.f, 0.f, 0.f, 0.f}, o = {0.f, 0.f, 0.f, 0.f};
            if (zbb) {
                const unsigned short* zr = zbb + (size_t)rowz * ZD_ + hi * 8;
                #pragma unroll
                for (int kk = 0; kk < 8; kk += 2) {
                    bf16x8 b0 = *(const bf16x8*)(zr + kk * 32);
                    bf16x8 b1 = *(const bf16x8*)(zr + kk * 32 + 32);
                    e = __builtin_amdgcn_mfma_f32_16x16x32_bf16(pav[kk],     b0, e, 0, 0, 0);
                    o = __builtin_amdgcn_mfma_f32_16x16x32_bf16(pav[kk + 1], b1, o, 0, 0, 0);
                }
            } else {
                const float* zr = zbF + (size_t)rowz * ZD_ + hi * 8;
                #pragma unroll
                for (int kk = 0; kk < 8; ++kk) {
                    float4 z0 = *(const float4*)(zr + kk * 32);
                    float4 z1 = *(const float4*)(zr + kk * 32 + 4);
                    unsigned short hh[8] = { f2b(z0.x), f2b(z0.y), f2b(z0.z), f2b(z0.w),
                                             f2b(z1.x), f2b(z1.y), f2b(z1.z), f2b(z1.w) };
                    bf16x8 bz = *(const bf16x8*)hh;
                    if (kk & 1) o = __builtin_amdgcn_mfma_f32_16x16x32_bf16(pav[kk], bz, o, 0, 0, 0);
                    else        e = __builtin_amdgcn_mfma_f32_16x16x32_bf16(pav[kk], bz, e, 0, 0, 0);
                }
            }
            scores[j2] = (rsel == 0) ? e[0] + o[0] : (rsel == 1) ? e[1] + o[1]
                       : (rsel == 2) ? e[2] + o[2] : e[3] + o[3];
        }
        // partial logsumexp over this half's subset
        float mx = scores[0];
        #pragma unroll
        for (int j2 = 1; j2 < 5; ++j2) mx = fmaxf(mx, scores[j2]);
        float se = 0.f;
        #pragma unroll
        for (int j2 = 0; j2 < 5; ++j2) se += __expf(scores[j2] - mx);
        if (half == 1 && owner) { bufm[r] = mx; bufs[r] = se; }
        __syncthreads();   // buf ready
        if (half == 0 && owner) {
            float m1 = bufm[r], s1 = bufs[r];
            float mt  = fmaxf(mx, m1);
            float set = se * __expf(mx - mt) + s1 * __expf(m1 - mt);
            if (gl < len_b) lsum += __logf(set) + mt - scores[0];
        }
    }
    if (half == 0) {
        #pragma unroll
        for (int sh = 1; sh < 64; sh <<= 1) lsum += __shfl_xor(lsum, sh);
        if (lane == 0) atomicAdd(&ws[0], lsum);
    }
}

__global__ void cnce_fin(const float* __restrict__ ws, float* __restrict__ out) {
    out[0] = ws[0] / ws[1];
}

extern "C" void kernel_launch(void* const* d_in, const int* in_sizes, int n_in,
                              void* d_out, int out_size, void* d_ws, size_t ws_size,
                              hipStream_t stream) {
    const float* c  = (const float*)d_in[0];
    const float* z  = (const float*)d_in[1];
    const float* W  = (const float*)d_in[2];
    const int* neg_shift = (const int*)d_in[3];
    const int* length    = (const int*)d_in[4];
    float* out = (float*)d_out;
    float* ws  = (float*)d_ws;
    unsigned short* WT = (unsigned short*)((char*)d_ws + 256);

    const size_t ZBF_OFF = 256 + (size_t)P_ * CD_ * ZD_ * 2;          // 1,573,120
    const size_t NEED    = ZBF_OFF + (size_t)B_ * L_ * ZD_ * 2;       // ~18.35 MB
    unsigned short* zbf = (ws_size >= NEED)
                        ? (unsigned short*)((char*)d_ws + ZBF_OFF) : nullptr;

    cnce_prep<<<4481, 256, 0, stream>>>(W, WT, z, zbf, length, ws);
    cnce_main<<<512, 512, 0, stream>>>(c, z, WT, zbf, neg_shift, length, ws);
    cnce_fin<<<1, 1, 0, stream>>>(ws, out);
}

// Round 10
// 255.505 us; speedup vs baseline: 1.6661x; 1.6026x over previous
//
#include <hip/hip_runtime.h>

#define B_   32
#define L_   1024
#define CD_  256
#define ZD_  256
#define P_   12
#define NEG_ 8
#define TL_  32    // l-rows per block

typedef __attribute__((ext_vector_type(8))) short bf16x8;
typedef __attribute__((ext_vector_type(4))) float f32x4;

// LDS map (dynamic): [0,131072) z-windows (8 x 32 rows x 512B, row-XOR swizzled)
//                    [131072,147456) Wc (32 rows x 512B, row-XOR swizzled)
//                    [147456,148224) pbuf: pbm[3][32], pbs[3][32]
#define LDS_TOTAL 148480
#define WC_OFF    131072
#define PB_OFF    147456

__device__ __forceinline__ unsigned short f2b(float f) {
    unsigned u = __float_as_uint(f);
    u += 0x7FFFu + ((u >> 16) & 1u);          // round-nearest-even
    return (unsigned short)(u >> 16);
}

__device__ __forceinline__ void glds16(const void* g, void* l) {
    __builtin_amdgcn_global_load_lds(
        (const __attribute__((address_space(1))) unsigned int*)g,
        (__attribute__((address_space(3))) unsigned int*)l, 16, 0, 0);
}

// ws: ws[0]=loss, ws[1]=msum; WT2 bf16 @byte 256 (12*8*4*2048 elems); zbf @byte 1573120
// prep: blk<96: WT2 transpose; [96,4192): z->bf16; 4192: init
__global__ __launch_bounds__(256) void cnce_prep(
        const float* __restrict__ W, unsigned short* __restrict__ WT2,
        const float* __restrict__ z, unsigned short* __restrict__ zbf,
        const int* __restrict__ length, float* __restrict__ ws) {
    const int blk = blockIdx.x;
    const int tid = threadIdx.x;
    if (blk < 96) {
        const int p = blk >> 3, kk = blk & 7, d = tid;
        #pragma unroll
        for (int hq = 0; hq < 4; ++hq) {
            unsigned short h[8];
            #pragma unroll
            for (int e = 0; e < 8; ++e)
                h[e] = f2b(W[((size_t)p * CD_ + kk * 32 + hq * 8 + e) * ZD_ + d]);
            *(int4*)(WT2 + (size_t)((p * 8 + kk) * 4 + hq) * 2048 + d * 8) = *(const int4*)h;
        }
    } else if (blk < 4192) {
        if (zbf) {
            size_t i = ((size_t)(blk - 96) * 256 + tid) * 8;
            float4 a = *(const float4*)(z + i), b = *(const float4*)(z + i + 4);
            unsigned short h[8] = { f2b(a.x), f2b(a.y), f2b(a.z), f2b(a.w),
                                    f2b(b.x), f2b(b.y), f2b(b.z), f2b(b.w) };
            *(int4*)(zbf + i) = *(const int4*)h;
        }
    } else {
        if (tid < 64) {
            int v = (tid < B_) ? length[tid] : 0;
            #pragma unroll
            for (int m = 1; m < 64; m <<= 1) v += __shfl_xor(v, m);
            if (tid == 0) { ws[0] = 0.f; ws[1] = (float)v; }
        }
    }
}

__global__ __launch_bounds__(512, 2) void cnce_main(
        const float* __restrict__ c, const float* __restrict__ z,
        const unsigned short* __restrict__ WT2,
        const unsigned short* __restrict__ zbf,
        const int* __restrict__ neg_shift,
        const int* __restrict__ length, float* __restrict__ ws) {
    extern __shared__ char smem[];
    char* zw  = smem;
    char* wcb = smem + WC_OFF;
    float* pbm = (float*)(smem + PB_OFF);
    float* pbs = pbm + 96;

    // XCD swizzle: 1024 blocks = 8 XCD x 128; XCD k gets b in [4k,4k+4)
    const int hbx  = blockIdx.x;
    const int work = ((hbx & 7) << 7) | (hbx >> 3);
    const int b  = work >> 5;
    const int l0 = (work & 31) * TL_;
    const int tid  = threadIdx.x;
    const int w    = tid >> 6;          // 0..7
    const int lane = tid & 63;
    const int hi   = lane >> 4;
    const int m    = lane & 15;
    const int rg   = w & 1;             // row-group: rows rg*16+m
    const int jg   = w >> 1;            // j-subset: 0:{pos,n0,n1} 1:{n2,n3} 2:{n4,n5} 3:{n6,n7}

    int sh8[NEG_];
    #pragma unroll
    for (int j = 0; j < NEG_; ++j) sh8[j] = neg_shift[j];
    const int len_b = length[b];
    const bool owner = (hi == (m >> 2));
    const int  rsel  = m & 3;
    const int  l     = rg * 16 + m;     // phase-B row within tile
    const int  gl    = l0 + l;

    // ---- stage c f32 into zw[0..32768) (linear dest, src col pre-XOR'd) ----
    {
        const char* cb = (const char*)(c + (size_t)(b * L_ + l0) * CD_);
        #pragma unroll
        for (int i = 0; i < 4; ++i) {
            int f = i * 8192 + w * 1024 + (lane << 4);
            int row = f >> 10, col = f & 1023;
            glds16(cb + ((size_t)row << 10) + (col ^ ((row & 7) << 4)),
                   zw + i * 8192 + w * 1024);
        }
    }
    __syncthreads();

    // ---- c fragments (MFMA B-operand) into registers ----
    bf16x8 cf[8][2];
    #pragma unroll
    for (int kk = 0; kk < 8; ++kk)
        #pragma unroll
        for (int ni = 0; ni < 2; ++ni) {
            int lr = ni * 16 + m;
            int cb0 = kk * 128 + hi * 32;
            float4 a  = *(const float4*)(zw + lr * 1024 + ((cb0)      ^ ((lr & 7) << 4)));
            float4 b4 = *(const float4*)(zw + lr * 1024 + ((cb0 + 16) ^ ((lr & 7) << 4)));
            unsigned short hh[8] = { f2b(a.x), f2b(a.y), f2b(a.z), f2b(a.w),
                                     f2b(b4.x), f2b(b4.y), f2b(b4.z), f2b(b4.w) };
            cf[kk][ni] = *(const bf16x8*)hh;
        }
    __syncthreads();

    // ---- stage 8 negative z-windows (bf16, row-XOR swizzled) ----
    if (zbf) {
        const unsigned short* zb = zbf + (size_t)b * L_ * ZD_;
        #pragma unroll
        for (int i = 0; i < 16; ++i) {
            int f = i * 8192 + w * 1024 + (lane << 4);
            int win = f >> 14, r = (f >> 9) & 31, col = f & 511;
            int zrow = (l0 + sh8[win] + r) & (L_ - 1);
            glds16(zb + (size_t)zrow * ZD_ + ((col ^ ((r & 7) << 4)) >> 1),
                   zw + i * 8192 + w * 1024);
        }
    } else {
        #pragma unroll
        for (int i = 0; i < 16; ++i) {
            int f = i * 8192 + tid * 16;
            int win = f >> 14, r = (f >> 9) & 31, col = f & 511;
            int zrow = (l0 + sh8[win] + r) & (L_ - 1);
            const float* zp = z + (size_t)(b * L_ + zrow) * ZD_ + ((col ^ ((r & 7) << 4)) >> 1);
            float4 a = *(const float4*)zp, b4 = *(const float4*)(zp + 4);
            unsigned short hh[8] = { f2b(a.x), f2b(a.y), f2b(a.z), f2b(a.w),
                                     f2b(b4.x), f2b(b4.y), f2b(b4.z), f2b(b4.w) };
            *(int4*)(zw + f) = *(const int4*)hh;
        }
    }

    const unsigned short* zbb = zbf ? zbf + (size_t)b * L_ * ZD_ : nullptr;
    const float* zbF = z + (size_t)b * L_ * ZD_;

    f32x4 acc[2][2];
    auto do_gemm = [&](int p) {
        #pragma unroll
        for (int mi = 0; mi < 2; ++mi)
            #pragma unroll
            for (int ni = 0; ni < 2; ++ni) acc[mi][ni] = (f32x4){0.f, 0.f, 0.f, 0.f};
        const unsigned short* wp = WT2 + (size_t)p * 8 * 4 * 2048;
        #pragma unroll
        for (int kk = 0; kk < 8; ++kk) {
            const unsigned short* sl = wp + (kk * 4 + hi) * 2048;
            bf16x8 wf0 = *(const bf16x8*)(sl + (w * 32 + m) * 8);
            bf16x8 wf1 = *(const bf16x8*)(sl + (w * 32 + 16 + m) * 8);
            acc[0][0] = __builtin_amdgcn_mfma_f32_16x16x32_bf16(wf0, cf[kk][0], acc[0][0], 0, 0, 0);
            acc[0][1] = __builtin_amdgcn_mfma_f32_16x16x32_bf16(wf0, cf[kk][1], acc[0][1], 0, 0, 0);
            acc[1][0] = __builtin_amdgcn_mfma_f32_16x16x32_bf16(wf1, cf[kk][0], acc[1][0], 0, 0, 0);
            acc[1][1] = __builtin_amdgcn_mfma_f32_16x16x32_bf16(wf1, cf[kk][1], acc[1][1], 0, 0, 0);
        }
    };
    auto do_spill = [&]() {
        #pragma unroll
        for (int mi = 0; mi < 2; ++mi)
            #pragma unroll
            for (int ni = 0; ni < 2; ++ni) {
                int lr = ni * 16 + m;
                int d0 = w * 32 + mi * 16 + hi * 4;
                unsigned short hh[4] = { f2b(acc[mi][ni][0]), f2b(acc[mi][ni][1]),
                                         f2b(acc[mi][ni][2]), f2b(acc[mi][ni][3]) };
                *(uint2*)(wcb + ((lr * 512 + d0 * 2) ^ ((lr & 15) << 4))) = *(const uint2*)hh;
            }
    };

    float lsum = 0.f;
    do_gemm(0);
    __syncthreads();
    do_spill();
    __syncthreads();

    for (int p = 0; p < P_; ++p) {
        if (p < P_ - 1) do_gemm(p + 1);      // interleaves with phase-B below
        // ---- phase B(p) ----
        bf16x8 pav[8];
        #pragma unroll
        for (int kk = 0; kk < 8; ++kk)
            pav[kk] = *(const bf16x8*)(wcb + ((l * 512 + kk * 64 + hi * 16) ^ ((l & 15) << 4)));
        const int NJ = (jg == 0) ? 3 : 2;
        float sc[3];
        sc[2] = -3e38f;
        #pragma unroll
        for (int j2 = 0; j2 < 3; ++j2) {
            if (j2 >= NJ) continue;
            f32x4 e = {0.f, 0.f, 0.f, 0.f}, o = {0.f, 0.f, 0.f, 0.f};
            if (jg == 0 && j2 == 0) {
                const int rowz = (gl + p + 1) & (L_ - 1);
                if (zbb) {
                    const unsigned short* zr = zbb + (size_t)rowz * ZD_ + hi * 8;
                    #pragma unroll
                    for (int kk = 0; kk < 8; kk += 2) {
                        e = __builtin_amdgcn_mfma_f32_16x16x32_bf16(pav[kk],     *(const bf16x8*)(zr + kk * 32),      e, 0, 0, 0);
                        o = __builtin_amdgcn_mfma_f32_16x16x32_bf16(pav[kk + 1], *(const bf16x8*)(zr + kk * 32 + 32), o, 0, 0, 0);
                    }
                } else {
                    const float* zr = zbF + (size_t)rowz * ZD_ + hi * 8;
                    #pragma unroll
                    for (int kk = 0; kk < 8; ++kk) {
                        float4 z0 = *(const float4*)(zr + kk * 32);
                        float4 z1 = *(const float4*)(zr + kk * 32 + 4);
                        unsigned short hh[8] = { f2b(z0.x), f2b(z0.y), f2b(z0.z), f2b(z0.w),
                                                 f2b(z1.x), f2b(z1.y), f2b(z1.z), f2b(z1.w) };
                        bf16x8 bz = *(const bf16x8*)hh;
                        if (kk & 1) o = __builtin_amdgcn_mfma_f32_16x16x32_bf16(pav[kk], bz, o, 0, 0, 0);
                        else        e = __builtin_amdgcn_mfma_f32_16x16x32_bf16(pav[kk], bz, e, 0, 0, 0);
                    }
                }
            } else {
                const int win = (jg == 0) ? (j2 - 1) : (2 * jg + j2);
                const char* base = zw + (win << 14) + l * 512;
                #pragma unroll
                for (int kk = 0; kk < 8; kk += 2) {
                    bf16x8 b0 = *(const bf16x8*)(base + ((kk * 64 + hi * 16)      ^ ((l & 7) << 4)));
                    bf16x8 b1 = *(const bf16x8*)(base + ((kk * 64 + 64 + hi * 16) ^ ((l & 7) << 4)));
                    e = __builtin_amdgcn_mfma_f32_16x16x32_bf16(pav[kk],     b0, e, 0, 0, 0);
                    o = __builtin_amdgcn_mfma_f32_16x16x32_bf16(pav[kk + 1], b1, o, 0, 0, 0);
                }
            }
            sc[j2] = (rsel == 0) ? e[0] + o[0] : (rsel == 1) ? e[1] + o[1]
                   : (rsel == 2) ? e[2] + o[2] : e[3] + o[3];
        }
        float mx = fmaxf(sc[0], sc[1]);
        if (NJ == 3) mx = fmaxf(mx, sc[2]);
        float se = __expf(sc[0] - mx) + __expf(sc[1] - mx);
        if (NJ == 3) se += __expf(sc[2] - mx);
        if (jg && owner) { pbm[(jg - 1) * 32 + l] = mx; pbs[(jg - 1) * 32 + l] = se; }
        __syncthreads();
        if (jg == 0) {
            float M = mx, S = se;
            #pragma unroll
            for (int q = 0; q < 3; ++q) {
                float pm = pbm[q * 32 + l], ps = pbs[q * 32 + l];
                float M2 = fmaxf(M, pm);
                S = S * __expf(M - M2) + ps * __expf(pm - M2);
                M = M2;
            }
            if (owner && gl < len_b) lsum += __logf(S) + M - sc[0];
        }
        if (p < P_ - 1) do_spill();
        __syncthreads();
    }

    if (jg == 0) {
        #pragma unroll
        for (int sh = 1; sh < 64; sh <<= 1) lsum += __shfl_xor(lsum, sh);
        if (lane == 0) atomicAdd(&ws[0], lsum);
    }
}

__global__ void cnce_fin(const float* __restrict__ ws, float* __restrict__ out) {
    out[0] = ws[0] / ws[1];
}

extern "C" void kernel_launch(void* const* d_in, const int* in_sizes, int n_in,
                              void* d_out, int out_size, void* d_ws, size_t ws_size,
                              hipStream_t stream) {
    const float* c  = (const float*)d_in[0];
    const float* z  = (const float*)d_in[1];
    const float* W  = (const float*)d_in[2];
    const int* neg_shift = (const int*)d_in[3];
    const int* length    = (const int*)d_in[4];
    float* out = (float*)d_out;
    float* ws  = (float*)d_ws;
    unsigned short* WT2 = (unsigned short*)((char*)d_ws + 256);

    const size_t ZBF_OFF = 256 + (size_t)P_ * CD_ * ZD_ * 2;          // 1,573,120
    const size_t NEED    = ZBF_OFF + (size_t)B_ * L_ * ZD_ * 2;       // ~18.35 MB
    unsigned short* zbf = (ws_size >= NEED)
                        ? (unsigned short*)((char*)d_ws + ZBF_OFF) : nullptr;

    (void)hipFuncSetAttribute((const void*)cnce_main,
                              hipFuncAttributeMaxDynamicSharedMemorySize, LDS_TOTAL);

    cnce_prep<<<4193, 256, 0, stream>>>(W, WT2, z, zbf, length, ws);
    cnce_main<<<1024, 512, LDS_TOTAL, stream>>>(c, z, WT2, zbf, neg_shift, length, ws);
    cnce_fin<<<1, 1, 0, stream>>>(ws, out);
}